// Round 6
// baseline (237.458 us; speedup 1.0000x reference)
//
#include <hip/hip_runtime.h>
#include <math.h>

// Hyena filter: k = MLP(z)·decay ; out = irfft(rfft(x,8192)*rfft(k,8192))[:4096] + x*bias
// FFT: rfft(8192 real) via complex FFT of N=4096 (even/odd packing).
// R9: radix-16 Stockham (3 passes, 256 threads x 16 cplx) replaces radix-8
//     (4 passes, 512 x 8). After fwd pass 3 each thread holds all 16 of its
//     bins Z[j+256r] in REGISTERS: combine exchanges only the 8 upper bins
//     with partner thread (256-j) via a stride-9 linear LDS region, and the
//     inverse pass 1 runs from registers. LDS ops 16->10 per element (-37%),
//     barriers 17->10 (-41%), twiddled passes 6->4 per row.
//     PAD(i)=i+(i>>4); identities: PAD(j+256r)=PAD(j)+272r ; PAD(16j+r)=17j+r ;
//     PAD(base+16r)=PAD(base)+17r. dft16 = 8x dft4 + 8 inner twiddles; its
//     outputs are base-4-digit-swapped -> compile-time PM(r) permutation.

#define TWO_PI 6.2831853071795864769f
#define C8 0.70710678118654752440f
#define PM(r) ((((r) & 3) << 2) | ((r) >> 2))

typedef __attribute__((ext_vector_type(2))) float cplx;

static __device__ __forceinline__ cplx mkc(float x, float y) { cplx c; c.x = x; c.y = y; return c; }
static __device__ __forceinline__ cplx caddi(cplx a, cplx b) { return mkc(a.x - b.y, a.y + b.x); } // a + i b
static __device__ __forceinline__ cplx csubi(cplx a, cplx b) { return mkc(a.x + b.y, a.y - b.x); } // a - i b
static __device__ __forceinline__ cplx cmulv(cplx a, cplx b) {
    return mkc(a.x * b.x - a.y * b.y, a.x * b.y + a.y * b.x);
}
static __device__ __forceinline__ cplx cmuljv(cplx a, cplx b) {  // conj(a)*b
    return mkc(a.x * b.x + a.y * b.y, a.x * b.y - a.y * b.x);
}

template <bool FWD>
__device__ __forceinline__ void dft4(cplx& a, cplx& b, cplx& c, cplx& d) {
    cplx t0 = a + c, t1 = a - c, t2 = b + d, t3 = b - d;
    a = t0 + t2; c = t0 - t2;
    if (FWD) { b = csubi(t1, t3); d = caddi(t1, t3); }
    else     { b = caddi(t1, t3); d = csubi(t1, t3); }
}

// stage B (inner twiddles) + stage C of the 16-point DFT (n = n0 + 4*n1 split).
// Input: v[n0+4m] = A_{n0}[m] (stage A = dft4 over columns). Output:
// X[m + 4*k1] at v[4m + k1]  ==> natural bin r lives at v[PM(r)].
template <bool FWD>
__device__ __forceinline__ void dft16_stageBC(cplx v[16]) {
    const float c1 = 0.92387953251128675613f, s1 = 0.38268343236508977173f;
    const cplx W1 = FWD ? mkc(c1, -s1) : mkc(c1, s1);
    const cplx W2 = FWD ? mkc(C8, -C8) : mkc(C8, C8);
    const cplx W3 = FWD ? mkc(s1, -c1) : mkc(s1, c1);
    const cplx W6 = FWD ? mkc(-C8, -C8) : mkc(-C8, C8);
    const cplx W9 = FWD ? mkc(-c1, s1) : mkc(-c1, -s1);
    v[5]  = cmulv(v[5],  W1);
    v[9]  = cmulv(v[9],  W2);
    v[13] = cmulv(v[13], W3);
    v[6]  = cmulv(v[6],  W2);
    v[10] = FWD ? mkc(v[10].y, -v[10].x) : mkc(-v[10].y, v[10].x);   // * (∓i)
    v[14] = cmulv(v[14], W6);
    v[7]  = cmulv(v[7],  W3);
    v[11] = cmulv(v[11], W6);
    v[15] = cmulv(v[15], W9);
    dft4<FWD>(v[0],  v[1],  v[2],  v[3]);
    dft4<FWD>(v[4],  v[5],  v[6],  v[7]);
    dft4<FWD>(v[8],  v[9],  v[10], v[11]);
    dft4<FWD>(v[12], v[13], v[14], v[15]);
}

template <bool FWD>
__device__ __forceinline__ void dft16(cplx v[16]) {
    dft4<FWD>(v[0], v[4], v[8],  v[12]);
    dft4<FWD>(v[1], v[5], v[9],  v[13]);
    dft4<FWD>(v[2], v[6], v[10], v[14]);
    dft4<FWD>(v[3], v[7], v[11], v[15]);
    dft16_stageBC<FWD>(v);
}

// w^1..w^15 from one sincos, shallow (depth<=4) cmul chains.
__device__ __forceinline__ void twiddle_powers16(float ang, cplx w[16]) {
    float s, c;
    __sincosf(ang, &s, &c);
    w[1]  = mkc(c, s);
    w[2]  = cmulv(w[1], w[1]);
    w[3]  = cmulv(w[2], w[1]);
    w[4]  = cmulv(w[2], w[2]);
    w[5]  = cmulv(w[4], w[1]);
    w[6]  = cmulv(w[3], w[3]);
    w[7]  = cmulv(w[4], w[3]);
    w[8]  = cmulv(w[4], w[4]);
    w[9]  = cmulv(w[8], w[1]);
    w[10] = cmulv(w[5], w[5]);
    w[11] = cmulv(w[8], w[3]);
    w[12] = cmulv(w[6], w[6]);
    w[13] = cmulv(w[8], w[5]);
    w[14] = cmulv(w[7], w[7]);
    w[15] = cmulv(w[8], w[7]);
}

// One radix-16 Stockham pass over N=4096 in LDS, in place. 256 threads.
template <int NS, bool FWD>
__device__ __forceinline__ void fft16_pass_ip(cplx* __restrict__ buf, int j) {
    cplx* rp = buf + (j + (j >> 4));
    cplx v[16];
#pragma unroll
    for (int r = 0; r < 16; r++) v[r] = rp[272 * r];
    if (NS > 1) {
        int jm = j & (NS - 1);
        float ang = (FWD ? -1.0f : 1.0f) * (TWO_PI / (float)(NS * 16)) * (float)jm;
        cplx w[16];
        twiddle_powers16(ang, w);
#pragma unroll
        for (int r = 1; r < 16; r++) v[r] = cmulv(v[r], w[r]);
    }
    dft16<FWD>(v);
    __syncthreads();                       // everyone done reading
    int base = ((j & ~(NS - 1)) << 4) + (j & (NS - 1));
    cplx* wp = buf + (base + (base >> 4));
#pragma unroll
    for (int r = 0; r < 16; r++) {
        const int off = (NS == 1) ? r : (NS == 16) ? (17 * r) : (272 * r);
        wp[off] = v[PM(r)];
    }
    __syncthreads();
}

// Forward pass 1 (NS=1) from registers; inputs z[j+256r], r<8; r>=8 zero.
// Zero-folded stage A: dft4(x0,x1,0,0) = {x0+x1, x0∓i x1, x0-x1, x0±i x1}.
__device__ __forceinline__ void fft16_pass1_fwd_regs(cplx* __restrict__ buf, int j,
                                                     const cplx xv[8]) {
    cplx v[16];
#pragma unroll
    for (int n0 = 0; n0 < 4; n0++) {
        cplx a = xv[n0], b = xv[n0 + 4];
        v[n0]      = a + b;
        v[n0 + 4]  = csubi(a, b);
        v[n0 + 8]  = a - b;
        v[n0 + 12] = caddi(a, b);
    }
    dft16_stageBC<true>(v);
    cplx* wp = buf + 17 * j;
#pragma unroll
    for (int r = 0; r < 16; r++) wp[r] = v[PM(r)];
    __syncthreads();
}

// ---------------- Kernel 1: positional MLP -> h3T (64 x 4096) ----------------
__global__ __launch_bounds__(256) void mlp_kernel(
    const float* __restrict__ zin, const float* __restrict__ W1,
    const float* __restrict__ b1, const float* __restrict__ freq,
    const float* __restrict__ W2, const float* __restrict__ b2,
    const float* __restrict__ W3, const float* __restrict__ b3,
    float* __restrict__ h3T) {
    __shared__ float hs1[64][64];
    __shared__ float hs2[64][64];
    int tid = threadIdx.x;
    int l = tid & 63, w = tid >> 6;
    int lg = blockIdx.x * 64 + l;          // grid = 64 blocks covers 4096

    float zf[5];
#pragma unroll
    for (int e = 0; e < 5; e++) zf[e] = zin[lg * 5 + e];

    // layer 1
#pragma unroll
    for (int i = 0; i < 16; i++) {
        int o = w * 16 + i;
        float a = b1[o];
#pragma unroll
        for (int e = 0; e < 5; e++) a += W1[o * 5 + e] * zf[e];
        hs1[o][l] = __sinf(freq[o] * a);
    }
    __syncthreads();

    // layer 2
    float acc[16];
#pragma unroll
    for (int i = 0; i < 16; i++) acc[i] = b2[w * 16 + i];
#pragma unroll 8
    for (int o = 0; o < 64; o++) {
        float hv = hs1[o][l];
#pragma unroll
        for (int i = 0; i < 16; i++) acc[i] += W2[(w * 16 + i) * 64 + o] * hv;
    }
#pragma unroll
    for (int i = 0; i < 16; i++)
        hs2[w * 16 + i][l] = __sinf(freq[w * 16 + i] * acc[i]);
    __syncthreads();

    // layer 3
#pragma unroll
    for (int i = 0; i < 16; i++) acc[i] = b3[w * 16 + i];
#pragma unroll 8
    for (int o = 0; o < 64; o++) {
        float hv = hs2[o][l];
#pragma unroll
        for (int i = 0; i < 16; i++) acc[i] += W3[(w * 16 + i) * 64 + o] * hv;
    }
#pragma unroll
    for (int i = 0; i < 16; i++)
        h3T[(size_t)(w * 16 + i) * 4096 + lg] = __sinf(freq[w * 16 + i] * acc[i]);
}

// -------- Kernel 2: k[d,l] = <h3[:,l], W4[d,:]> * exp(-t[l]*|delta[d]|) --------
__global__ __launch_bounds__(256) void kgemm_kernel(
    const float* __restrict__ h3T, const float* __restrict__ W4,
    const float* __restrict__ tvec, const float* __restrict__ deltas,
    float* __restrict__ kout) {
    int lt = blockIdx.x & 3;       // l tile (4 x 1024)
    int dt = blockIdx.x >> 2;      // d tile (64 x 16)
    int l0 = lt * 1024 + threadIdx.x * 4;
    float4 acc[16];
#pragma unroll
    for (int i = 0; i < 16; i++) acc[i] = make_float4(0.f, 0.f, 0.f, 0.f);
#pragma unroll 8
    for (int o = 0; o < 64; o++) {
        float4 h = *(const float4*)(h3T + (size_t)o * 4096 + l0);
#pragma unroll
        for (int i = 0; i < 16; i++) {
            float wv = W4[(size_t)(dt * 16 + i) * 64 + o];
            acc[i].x += wv * h.x; acc[i].y += wv * h.y;
            acc[i].z += wv * h.z; acc[i].w += wv * h.w;
        }
    }
    float4 tl = *(const float4*)(tvec + l0);
#pragma unroll
    for (int i = 0; i < 16; i++) {
        int d = dt * 16 + i;
        float da = fabsf(deltas[d]);
        float4 o;
        o.x = acc[i].x * __expf(-tl.x * da);
        o.y = acc[i].y * __expf(-tl.y * da);
        o.z = acc[i].z * __expf(-tl.z * da);
        o.w = acc[i].w * __expf(-tl.w * da);
        *(float4*)(kout + (size_t)d * 4096 + l0) = o;
    }
}

// W32^i = e^{-2*pi*i*i/32}, i=0..7 (combine twiddle per 256-stride bin step)
#define W32_TABLE                                                             \
    const cplx W32C[8] = {                                                    \
        mkc(1.0f, 0.0f),                                                      \
        mkc(0.98078528040323044913f, -0.19509032201612826785f),               \
        mkc(0.92387953251128675613f, -0.38268343236508977173f),               \
        mkc(0.83146961230254523708f, -0.55557023301960222474f),               \
        mkc(0.70710678118654752440f, -0.70710678118654752440f),               \
        mkc(0.55557023301960222474f, -0.83146961230254523708f),               \
        mkc(0.38268343236508977173f, -0.92387953251128675613f),               \
        mkc(0.19509032201612826785f, -0.98078528040323044913f)};

// ------- Kernel 3: per-channel rfft(k,8192) -> Kf[d][0..4096] -------
// Kf stored with 1/4096 inverse-FFT scale folded in. Row stride 4104 complexes.
__global__ __launch_bounds__(256) void filter_fft_kernel(
    const float* __restrict__ kin, cplx* __restrict__ Kf) {
    __shared__ cplx buf[4352];
    int d = blockIdx.x, j = threadIdx.x;

    const cplx* k2 = (const cplx*)(kin + (size_t)d * 4096);
    cplx xv[8];
#pragma unroll
    for (int r = 0; r < 8; r++) xv[r] = k2[j + (r << 8)];
    fft16_pass1_fwd_regs(buf, j, xv);
    fft16_pass_ip<16, true>(buf, j);

    // fwd pass 3 (NS=256) fused: keep all 16 bins Z[j+256r] in regs
    cplx zv[16];
    {
        cplx* rp = buf + (j + (j >> 4));
#pragma unroll
        for (int r = 0; r < 16; r++) zv[r] = rp[272 * r];
        cplx w[16];
        twiddle_powers16(-TWO_PI * (float)j * (1.0f / 4096.0f), w);
#pragma unroll
        for (int r = 1; r < 16; r++) zv[r] = cmulv(zv[r], w[r]);
        dft16<true>(zv);
    }
    __syncthreads();                       // pass-2 data dead; linear region free

    // exchange upper 8 bins via linear region (stride 9 breaks bank aliasing)
#pragma unroll
    for (int s = 0; s < 8; s++) buf[9 * j + s] = zv[PM(8 + s)];
    __syncthreads();

    const float scale = 1.0f / 4096.0f;
    float sb, cb;
    __sincosf(-TWO_PI * (float)j * (1.0f / 8192.0f), &sb, &cb);
    cplx w0 = mkc(cb, sb);
    W32_TABLE
    cplx* KfRow = Kf + (size_t)d * 4104;
    if (j == 0) {
        cplx z0 = zv[PM(0)];
        KfRow[0]    = mkc((z0.x + z0.y) * scale, 0.f);
        KfRow[4096] = mkc((z0.x - z0.y) * scale, 0.f);
        cplx zm = buf[0];                  // Z[2048]
        KfRow[2048] = mkc(zm.x * scale, -zm.y * scale);
#pragma unroll
        for (int i = 1; i < 8; i++) {
            cplx Zk = zv[PM(i)];
            cplx Zq = buf[8 - i];          // Z[256*(16-i)]
            cplx wk = cmulv(w0, W32C[i]);  // w0=(1,0) here, kept uniform
            cplx Fe = mkc(0.5f * (Zk.x + Zq.x), 0.5f * (Zk.y - Zq.y));
            cplx Fo = mkc(0.5f * (Zk.y + Zq.y), 0.5f * (Zq.x - Zk.x));
            cplx WFo = cmulv(wk, Fo);
            KfRow[256 * i]        = scale * (Fe + WFo);
            cplx t = Fe - WFo;
            KfRow[4096 - 256 * i] = mkc(scale * t.x, -scale * t.y);
        }
    } else {
        int p = 256 - j;
        cplx* kfp = KfRow + j;
        cplx* kfq = KfRow + (4096 - j);
#pragma unroll
        for (int i = 0; i < 8; i++) {
            cplx Zk = zv[PM(i)];
            cplx Zq = buf[9 * p + 7 - i];  // Z[4096-j-256i]
            cplx wk = (i == 0) ? w0 : cmulv(w0, W32C[i]);
            cplx Fe = mkc(0.5f * (Zk.x + Zq.x), 0.5f * (Zk.y - Zq.y));
            cplx Fo = mkc(0.5f * (Zk.y + Zq.y), 0.5f * (Zq.x - Zk.x));
            cplx WFo = cmulv(wk, Fo);
            kfp[256 * i]  = scale * (Fe + WFo);
            cplx t = Fe - WFo;
            kfq[-256 * i] = mkc(scale * t.x, -scale * t.y);
        }
    }
}

// ------- Kernel 4: per (b,d) row: FFT -> spectral multiply -> IFFT -> +x*bias -------
__global__ __launch_bounds__(256) void conv_kernel(
    const float* __restrict__ x, const cplx* __restrict__ Kf,
    const float* __restrict__ bias, float* __restrict__ out) {
    __shared__ cplx buf[4352];
    int rid = blockIdx.x;          // rid = b*1024 + d
    int d = rid & 1023;
    int j = threadIdx.x;

    const cplx* x2 = (const cplx*)(x + (size_t)rid * 4096);
    cplx xv[8];
#pragma unroll
    for (int r = 0; r < 8; r++) xv[r] = x2[j + (r << 8)];
    fft16_pass1_fwd_regs(buf, j, xv);
    fft16_pass_ip<16, true>(buf, j);

    // fwd pass 3 (NS=256) fused: all 16 bins Z[j+256r] stay in registers
    cplx zv[16];
    {
        cplx* rp = buf + (j + (j >> 4));
#pragma unroll
        for (int r = 0; r < 16; r++) zv[r] = rp[272 * r];
        cplx w[16];
        twiddle_powers16(-TWO_PI * (float)j * (1.0f / 4096.0f), w);
#pragma unroll
        for (int r = 1; r < 16; r++) zv[r] = cmulv(zv[r], w[r]);
        dft16<true>(zv);
    }
    __syncthreads();

    // exchange upper 8 bins with partner thread via linear region (stride 9)
#pragma unroll
    for (int s = 0; s < 8; s++) buf[9 * j + s] = zv[PM(8 + s)];
    __syncthreads();

    // combine against Kf; Z' lower bins stay in regs, partner-upper written back
    cplx yl[8];
    {
        float sb, cb;
        __sincosf(-TWO_PI * (float)j * (1.0f / 8192.0f), &sb, &cb);
        cplx w0 = mkc(cb, sb);
        W32_TABLE
        const cplx* KfRow = Kf + (size_t)d * 4104;
        if (j == 0) {
            cplx z0 = zv[PM(0)];
            float U0 = z0.x + z0.y, UN = z0.x - z0.y;
            float Y0 = U0 * KfRow[0].x, YN = UN * KfRow[4096].x;
            yl[0] = mkc(0.5f * (Y0 + YN), 0.5f * (Y0 - YN));
            cplx zm = buf[0];                              // Z[2048]
            cplx Km = KfRow[2048];
            cplx Ym = cmuljv(zm, Km);                      // conj(Z)*K
            buf[0] = mkc(Ym.x, -Ym.y);                     // Z'[2048]
#pragma unroll
            for (int i = 1; i < 8; i++) {
                cplx Zk = zv[PM(i)];
                cplx Zq = buf[8 - i];
                cplx K1 = KfRow[256 * i], K2 = KfRow[4096 - 256 * i];
                cplx wk = cmulv(w0, W32C[i]);
                cplx Fe = mkc(0.5f * (Zk.x + Zq.x), 0.5f * (Zk.y - Zq.y));
                cplx Fo = mkc(0.5f * (Zk.y + Zq.y), 0.5f * (Zq.x - Zk.x));
                cplx WFo = cmulv(wk, Fo);
                cplx U1 = Fe + WFo;
                cplx U2 = mkc(Fe.x - WFo.x, WFo.y - Fe.y);
                cplx Y1 = cmulv(U1, K1);
                cplx Y2 = cmulv(U2, K2);
                cplx FeY = mkc(0.5f * (Y1.x + Y2.x), 0.5f * (Y1.y - Y2.y));
                cplx T   = mkc(0.5f * (Y1.x - Y2.x), 0.5f * (Y1.y + Y2.y));
                cplx FoY = cmuljv(wk, T);
                yl[i] = caddi(FeY, FoY);
                buf[8 - i] = mkc(FeY.x + FoY.y, FoY.x - FeY.y);  // Z'[256(16-i)]
            }
        } else {
            int p = 256 - j;
            const cplx* kfp = KfRow + j;
            const cplx* kfq = KfRow + (4096 - j);
#pragma unroll
            for (int i = 0; i < 8; i++) {
                cplx Zk = zv[PM(i)];
                cplx Zq = buf[9 * p + 7 - i];
                cplx K1 = kfp[256 * i], K2 = kfq[-256 * i];
                cplx wk = (i == 0) ? w0 : cmulv(w0, W32C[i]);
                cplx Fe = mkc(0.5f * (Zk.x + Zq.x), 0.5f * (Zk.y - Zq.y));
                cplx Fo = mkc(0.5f * (Zk.y + Zq.y), 0.5f * (Zq.x - Zk.x));
                cplx WFo = cmulv(wk, Fo);
                cplx U1 = Fe + WFo;
                cplx U2 = mkc(Fe.x - WFo.x, WFo.y - Fe.y);
                cplx Y1 = cmulv(U1, K1);
                cplx Y2 = cmulv(U2, K2);
                cplx FeY = mkc(0.5f * (Y1.x + Y2.x), 0.5f * (Y1.y - Y2.y));
                cplx T   = mkc(0.5f * (Y1.x - Y2.x), 0.5f * (Y1.y + Y2.y));
                cplx FoY = cmuljv(wk, T);
                yl[i] = caddi(FeY, FoY);
                buf[9 * p + 7 - i] = mkc(FeY.x + FoY.y, FoY.x - FeY.y);
            }
        }
    }
    __syncthreads();

    // gather own upper Z' and run inverse pass 1 entirely from registers
    cplx uv[16];
#pragma unroll
    for (int i = 0; i < 8; i++) uv[i] = yl[i];
#pragma unroll
    for (int s = 0; s < 8; s++) uv[8 + s] = buf[9 * j + s];
    __syncthreads();                       // linear region reads done before overwrite
    dft16<false>(uv);
    {
        cplx* wp = buf + 17 * j;
#pragma unroll
        for (int r = 0; r < 16; r++) wp[r] = uv[PM(r)];
    }
    __syncthreads();
    fft16_pass_ip<16, false>(buf, j);

    // inverse pass 3 (NS=256): twiddle + stages A,B + lower-half stage C, fused store
    {
        cplx* rp = buf + (j + (j >> 4));
        cplx v[16];
#pragma unroll
        for (int r = 0; r < 16; r++) v[r] = rp[272 * r];
        cplx w[16];
        twiddle_powers16(TWO_PI * (float)j * (1.0f / 4096.0f), w);
#pragma unroll
        for (int r = 1; r < 16; r++) v[r] = cmulv(v[r], w[r]);
        // stage A (inverse)
        dft4<false>(v[0], v[4], v[8],  v[12]);
        dft4<false>(v[1], v[5], v[9],  v[13]);
        dft4<false>(v[2], v[6], v[10], v[14]);
        dft4<false>(v[3], v[7], v[11], v[15]);
        // stage B (inverse twiddles)
        const float c1 = 0.92387953251128675613f, s1 = 0.38268343236508977173f;
        v[5]  = cmulv(v[5],  mkc(c1, s1));
        v[9]  = cmulv(v[9],  mkc(C8, C8));
        v[13] = cmulv(v[13], mkc(s1, c1));
        v[6]  = cmulv(v[6],  mkc(C8, C8));
        v[10] = mkc(-v[10].y, v[10].x);
        v[14] = cmulv(v[14], mkc(-C8, C8));
        v[7]  = cmulv(v[7],  mkc(s1, c1));
        v[11] = cmulv(v[11], mkc(-C8, C8));
        v[15] = cmulv(v[15], mkc(-c1, -s1));
        // stage C lower half only: X[m] and X[m+4], m=0..3  (outputs j+256r, r<8)
        float bd = bias[d];
        cplx* o2 = (cplx*)(out + (size_t)rid * 4096);
#pragma unroll
        for (int m = 0; m < 4; m++) {
            cplx t0 = v[4 * m] + v[4 * m + 2];
            cplx t1 = v[4 * m] - v[4 * m + 2];
            cplx t2 = v[4 * m + 1] + v[4 * m + 3];
            cplx t3 = v[4 * m + 1] - v[4 * m + 3];
            cplx Xa = t0 + t2;                 // X[m]
            cplx Xb = caddi(t1, t3);           // X[m+4] (inverse)
            o2[j + 256 * m]       = Xa + bd * xv[m];
            o2[j + 256 * (m + 4)] = Xb + bd * xv[m + 4];
        }
    }
}

extern "C" void kernel_launch(void* const* d_in, const int* in_sizes, int n_in,
                              void* d_out, int out_size, void* d_ws, size_t ws_size,
                              hipStream_t stream) {
    const float* x      = (const float*)d_in[0];
    // d_in[1] = L (int scalar) — compile-time constant 4096 here
    const float* zin    = (const float*)d_in[2];
    const float* tvec   = (const float*)d_in[3];
    const float* deltas = (const float*)d_in[4];
    const float* W1     = (const float*)d_in[5];
    const float* b1     = (const float*)d_in[6];
    const float* freq   = (const float*)d_in[7];
    const float* W2     = (const float*)d_in[8];
    const float* b2     = (const float*)d_in[9];
    const float* W3     = (const float*)d_in[10];
    const float* b3     = (const float*)d_in[11];
    const float* W4     = (const float*)d_in[12];
    const float* bias   = (const float*)d_in[13];
    float* out = (float*)d_out;

    // ws layout: h3T (64 x 4096 f32 = 1 MB) | Kf (1024 rows * 4104 cplx = 33.6 MB)
    float* h3T = (float*)d_ws;
    cplx*  Kf  = (cplx*)((char*)d_ws + (size_t)64 * 4096 * sizeof(float));
    // k (1024x4096 f32 = 16 MB) staged in the tail of d_out (64 MB); conv
    // overwrites it afterwards (stream-ordered: kgemm -> filter_fft -> conv).
    float* kbuf = out + (size_t)3072 * 4096;

    mlp_kernel<<<64, 256, 0, stream>>>(zin, W1, b1, freq, W2, b2, W3, b3, h3T);
    kgemm_kernel<<<256, 256, 0, stream>>>(h3T, W4, tvec, deltas, kbuf);
    filter_fft_kernel<<<1024, 256, 0, stream>>>(kbuf, Kf);
    conv_kernel<<<4096, 256, 0, stream>>>(x, Kf, bias, out);
}